// Round 1
// baseline (202.862 us; speedup 1.0000x reference)
//
#include <hip/hip_runtime.h>
#include <hip/hip_bf16.h>

// GAT on MI355X. Inputs fp32 (+ int32 adj); output fp32 [8 | 4096*8].
//  kA0: W[4][4096][8] fp32 -> Wt[32][4096] bf16 (transposed, B-operand layout)
//  kA : Wh[h][n][8] fp32 = x @ W_h via MFMA bf16 (x converted in-flight);
//       epilogue: s_src/s_dst = Wh . a1/a2  (kB fused away)
//  kC : mhat[h] = max_n s_dst[h][n]   (upper bound for softmax shift)
//  kD : fused masked-softmax attention + aggregation + head-mean -> d_out+8
//  kE : per-row log_softmax + w_lin partial sums
//  kF : out[8] = sum partials + b_lin -> d_out[0..8)

typedef __attribute__((ext_vector_type(8))) short bf16x8;   // MFMA A/B frag (4 VGPRs)
typedef __attribute__((ext_vector_type(4))) float f32x4;

#define NN 4096
#define NC 8

__device__ __forceinline__ short f2bf(float f) {
  __hip_bfloat16 h = __float2bfloat16(f);
  return *reinterpret_cast<short*>(&h);
}

__device__ __forceinline__ bool is_adj(const void* p) {
  const unsigned* u = (const unsigned*)p;
  unsigned m = u[0] | u[1] | u[2] | u[3] | u[100] | u[1000];
  return m <= 1u;   // adj dwords are 0/1; fp32 N(0,1) bits never <= 1
}

// ---------- kA0: W[h][f][o] fp32 -> Wt[h*8+o][f] bf16 ----------
__global__ __launch_bounds__(256) void kA0(const float* __restrict__ W, short* __restrict__ Wt) {
  int idx = blockIdx.x * 256 + threadIdx.x;      // 131072
  int h = idx >> 15, r = idx & 32767, f = r >> 3, o = r & 7;
  Wt[(size_t)(h * 8 + o) * NN + f] = f2bf(W[idx]);
}

// ---------- kA: Wh = x @ W via MFMA 16x16x32 bf16, + scores ----------
// 256 blocks x 256 thr (4 waves). Block: 16 rows x 32 cols; wave w: k in [w*1024, (w+1)*1024).
// A-frag: A[m=lane&15][k=q*8+j]; B-frag: B[k=q*8+j][n=lane&15] (from Wt rows).
// D: n=lane&15, m=q*4+reg  [m89/m91-verified layout].
__global__ __launch_bounds__(256) void kA(const void* __restrict__ c0, const void* __restrict__ c1,
                                          const short* __restrict__ Wt,
                                          float* __restrict__ Wh, float* __restrict__ ssrc,
                                          float* __restrict__ sdst, const float* __restrict__ a) {
  const float* x = (const float*)(is_adj(c0) ? c1 : c0);
  int m0 = blockIdx.x * 16;
  int t = threadIdx.x;
  int w = t >> 6, lane = t & 63;
  int mr = lane & 15, q = lane >> 4;
  const f32x4*  ap  = (const f32x4*)(x + (size_t)(m0 + mr) * NN + w * 1024 + q * 8);
  const bf16x8* b0p = (const bf16x8*)(Wt + (size_t)mr        * NN + w * 1024 + q * 8);
  const bf16x8* b1p = (const bf16x8*)(Wt + (size_t)(16 + mr) * NN + w * 1024 + q * 8);
  f32x4 acc0 = {0.f, 0.f, 0.f, 0.f}, acc1 = {0.f, 0.f, 0.f, 0.f};
#pragma unroll 4
  for (int kk = 0; kk < 32; ++kk) {      // 32 k-steps of 32
    f32x4 xa = ap[kk * 8];
    f32x4 xb = ap[kk * 8 + 1];
    bf16x8 af;
#pragma unroll
    for (int e = 0; e < 4; ++e) { af[e] = f2bf(xa[e]); af[4 + e] = f2bf(xb[e]); }
    bf16x8 b0 = b0p[kk * 4];
    bf16x8 b1 = b1p[kk * 4];
    acc0 = __builtin_amdgcn_mfma_f32_16x16x32_bf16(af, b0, acc0, 0, 0, 0);
    acc1 = __builtin_amdgcn_mfma_f32_16x16x32_bf16(af, b1, acc1, 0, 0, 0);
  }
  __shared__ float red[4][16][32];
  __shared__ float whole[16][32];
#pragma unroll
  for (int r = 0; r < 4; ++r) {
    red[w][q * 4 + r][mr]      = acc0[r];
    red[w][q * 4 + r][16 + mr] = acc1[r];
  }
  __syncthreads();
  for (int idx = t; idx < 512; idx += 256) {
    int m = idx >> 5, c = idx & 31;
    float s = red[0][m][c] + red[1][m][c] + red[2][m][c] + red[3][m][c];
    whole[m][c] = s;
    int h = c >> 3, o = c & 7;
    Wh[((size_t)h * NN + m0 + m) * NC + o] = s;
  }
  __syncthreads();
  if (t < 64) {
    int h = t >> 4, m = t & 15;
    float s1 = 0.f, s2 = 0.f;
#pragma unroll
    for (int o = 0; o < 8; ++o) {
      float v = whole[m][h * 8 + o];
      s1 += v * a[h * 16 + o];
      s2 += v * a[h * 16 + 8 + o];
    }
    ssrc[h * NN + m0 + m] = s1;
    sdst[h * NN + m0 + m] = s2;
  }
}

// ---------- kC: per-head global max of s_dst ----------
__global__ __launch_bounds__(256) void kC(const float* __restrict__ sdst, float* __restrict__ mhat) {
  int h = blockIdx.x, t = threadIdx.x;
  float m = -1e30f;
  for (int n = t; n < NN; n += 256) m = fmaxf(m, sdst[h * NN + n]);
  for (int mm = 1; mm <= 32; mm <<= 1) m = fmaxf(m, __shfl_xor(m, mm));
  __shared__ float sm[4];
  if ((t & 63) == 0) sm[t >> 6] = m;
  __syncthreads();
  if (t == 0) mhat[h] = fmaxf(fmaxf(sm[0], sm[1]), fmaxf(sm[2], sm[3]));
}

// ---------- kD: fused attention + aggregation + head-mean -> fp32 node_emb ----------
__global__ __launch_bounds__(256) void kD(const void* __restrict__ c0, const void* __restrict__ c1,
                                          const float* __restrict__ Wh,
                                          const float* __restrict__ ssrcg, const float* __restrict__ sdstg,
                                          const float* __restrict__ mhat,
                                          float* __restrict__ neF) {
  const int* adj = (const int*)(is_adj(c0) ? c0 : c1);
  __shared__ float whc[4][256][12];
  __shared__ int   adjt[8][257];
  __shared__ float sdl[4][256];
  __shared__ float red2[4][8][8];
  int t = threadIdx.x;
  int h = t >> 6, lane = t & 63;
  int sub = lane & 15, ig = lane >> 4;
  int i0 = blockIdx.x * 8;

  float mh = mhat[h];
  float ssr0 = ssrcg[h * NN + i0 + 2 * ig + 0];
  float ssr1 = ssrcg[h * NN + i0 + 2 * ig + 1];
  float tb0 = ssr0 + mh, tb1 = ssr1 + mh;
  float eb0 = fmaxf(tb0, 0.2f * tb0);
  float eb1 = fmaxf(tb1, 0.2f * tb1);
  float l0 = 0.f, l1 = 0.f;
  f32x4 a00 = {0,0,0,0}, a01 = {0,0,0,0}, a10 = {0,0,0,0}, a11 = {0,0,0,0};

  for (int jc = 0; jc < NN; jc += 256) {
    __syncthreads();
#pragma unroll
    for (int r = 0; r < 8; ++r)
      adjt[r][t] = adj[(size_t)(i0 + r) * NN + jc + t];
#pragma unroll
    for (int rep = 0; rep < 8; ++rep) {
      int idx = rep * 1024 + t * 4;
      int hh = idx >> 11, r1 = idx & 2047, jl = r1 >> 3, o0 = r1 & 7;
      f32x4 v = *(const f32x4*)(Wh + (size_t)hh * (NN * NC) + (size_t)(jc + jl) * NC + o0);
      *(f32x4*)&whc[hh][jl][o0] = v;
    }
    {
      int hh = t >> 6, jl = (t & 63) * 4;
      *(f32x4*)&sdl[hh][jl] = *(const f32x4*)(sdstg + (size_t)hh * NN + jc + jl);
    }
    __syncthreads();
#pragma unroll 2
    for (int jj = 0; jj < 16; ++jj) {
      int j = sub + jj * 16;
      float sd = sdl[h][j];
      f32x4 wv0 = *(const f32x4*)&whc[h][j][0];
      f32x4 wv1 = *(const f32x4*)&whc[h][j][4];
      int av0 = adjt[2 * ig + 0][j];
      int av1 = adjt[2 * ig + 1][j];
      float t0 = ssr0 + sd, t1 = ssr1 + sd;
      float e0 = fmaxf(t0, 0.2f * t0);
      float e1 = fmaxf(t1, 0.2f * t1);
      float w0 = __expf(e0 - eb0);
      float w1 = __expf(e1 - eb1);
      w0 = (av0 > 0) ? w0 : 0.f;
      w1 = (av1 > 0) ? w1 : 0.f;
      l0 += w0; l1 += w1;
      a00 += w0 * wv0; a01 += w0 * wv1;
      a10 += w1 * wv0; a11 += w1 * wv1;
    }
  }
#pragma unroll
  for (int m = 1; m <= 8; m <<= 1) {
    l0 += __shfl_xor(l0, m);
    l1 += __shfl_xor(l1, m);
#pragma unroll
    for (int e = 0; e < 4; ++e) {
      a00[e] += __shfl_xor(a00[e], m);
      a01[e] += __shfl_xor(a01[e], m);
      a10[e] += __shfl_xor(a10[e], m);
      a11[e] += __shfl_xor(a11[e], m);
    }
  }
  if (sub == 0) {
    float i0v = 1.f / l0, i1v = 1.f / l1;
#pragma unroll
    for (int e = 0; e < 4; ++e) {
      red2[h][2 * ig + 0][e]     = a00[e] * i0v;
      red2[h][2 * ig + 0][4 + e] = a01[e] * i0v;
      red2[h][2 * ig + 1][e]     = a10[e] * i1v;
      red2[h][2 * ig + 1][4 + e] = a11[e] * i1v;
    }
  }
  __syncthreads();
  if (t < 64) {
    int i = t >> 3, o = t & 7;
    float ne = 0.25f * (red2[0][i][o] + red2[1][i][o] + red2[2][i][o] + red2[3][i][o]);
    neF[(size_t)(i0 + i) * NC + o] = ne;
  }
}

// ---------- kE: log_softmax rows + w_lin partial sums ----------
__global__ __launch_bounds__(128) void kE(const float* __restrict__ neF, const float* __restrict__ wlin,
                                          float* __restrict__ partials) {
  int t = threadIdx.x;
  int n = blockIdx.x * 128 + t;
  f32x4 v0 = *(const f32x4*)(neF + (size_t)n * NC);
  f32x4 v1 = *(const f32x4*)(neF + (size_t)n * NC + 4);
  float m = v0[0];
#pragma unroll
  for (int e = 1; e < 4; ++e) m = fmaxf(m, v0[e]);
#pragma unroll
  for (int e = 0; e < 4; ++e) m = fmaxf(m, v1[e]);
  float s = 0.f;
#pragma unroll
  for (int e = 0; e < 4; ++e) s += __expf(v0[e] - m);
#pragma unroll
  for (int e = 0; e < 4; ++e) s += __expf(v1[e] - m);
  float ln = m + __logf(s);
  float wl = wlin[n];
  float p[8];
#pragma unroll
  for (int e = 0; e < 4; ++e) p[e] = (v0[e] - ln) * wl;
#pragma unroll
  for (int e = 0; e < 4; ++e) p[4 + e] = (v1[e] - ln) * wl;
#pragma unroll
  for (int mm = 1; mm <= 32; mm <<= 1)
#pragma unroll
    for (int o = 0; o < 8; ++o) p[o] += __shfl_xor(p[o], mm);
  __shared__ float wsum[2][8];
  if ((t & 63) == 0)
#pragma unroll
    for (int o = 0; o < 8; ++o) wsum[t >> 6][o] = p[o];
  __syncthreads();
  if (t < 8) partials[blockIdx.x * 8 + t] = wsum[0][t] + wsum[1][t];
}

// ---------- kF: final out[8] ----------
__global__ __launch_bounds__(64) void kF(const float* __restrict__ partials, const float* __restrict__ blin,
                                         float* __restrict__ out) {
  int t = threadIdx.x;
  if (t < 8) {
    float s = blin[0];
    for (int b = 0; b < 32; ++b) s += partials[b * 8 + t];
    out[t] = s;
  }
}

extern "C" void kernel_launch(void* const* d_in, const int* in_sizes, int n_in,
                              void* d_out, int out_size, void* d_ws, size_t ws_size,
                              hipStream_t stream) {
  const void* big0 = nullptr; const void* big1 = nullptr;
  const float* W = nullptr; const float* a = nullptr;
  const float* wlin = nullptr; const float* blin = nullptr;
  for (int idx = 0; idx < n_in; ++idx) {
    int sz = in_sizes[idx];
    if (sz == NN * NN)          { if (!big0) big0 = d_in[idx]; else big1 = d_in[idx]; }
    else if (sz == 4 * NN * NC) W    = (const float*)d_in[idx];
    else if (sz == 64)          a    = (const float*)d_in[idx];
    else if (sz == NN)          wlin = (const float*)d_in[idx];
    else if (sz == 1)           blin = (const float*)d_in[idx];
  }
  float* outF = (float*)d_out;       // fp32: [8] out | [4096][8] node_embeddings
  float* neF  = outF + 8;

  char* ws = (char*)d_ws;                 // 918,784 B total
  short* Wt      = (short*)(ws + 0);      // 262144 B
  float* Wh      = (float*)(ws + 262144); // 524288 B
  float* ssrc    = (float*)(ws + 786432); // 65536 B
  float* sdst    = (float*)(ws + 851968); // 65536 B
  float* mhat    = (float*)(ws + 917504); // 256 B
  float* partials= (float*)(ws + 917760); // 1024 B

  kA0<<<512, 256, 0, stream>>>(W, Wt);
  kA <<<256, 256, 0, stream>>>(big0, big1, Wt, Wh, ssrc, sdst, a);
  kC <<<4,   256, 0, stream>>>(sdst, mhat);
  kD <<<512, 256, 0, stream>>>(big0, big1, Wh, ssrc, sdst, mhat, neF);
  kE <<<32,  128, 0, stream>>>(neF, wlin, partials);
  kF <<<1,   64,  0, stream>>>(partials, blin, outF);
}

// Round 2
// 200.379 us; speedup vs baseline: 1.0124x; 1.0124x over previous
//
#include <hip/hip_runtime.h>
#include <hip/hip_bf16.h>

// GAT on MI355X. Inputs fp32 (+ int32 adj); output fp32 [8 | 4096*8].
//  kA0: W[4][4096][8] fp32 -> Wt[32][4096] bf16 (B-operand layout);
//       + init WhT rows 8..15 (col-8 = ones row for softmax denom, 9..15 = 0)
//  kA : Wh = x @ W_h via MFMA bf16; epilogue writes WhT[h][o][n] bf16 (transposed)
//       + s_src/s_dst = Wh . a1/a2
//  kC : mhat[h] = max_n s_dst[h][n]   (upper bound for softmax shift)
//  kD : MFMA attention: A-frag = exp-weights (in-register, bf16), B = WhT,
//       col 8 of B = 1.0 -> D col 8 = softmax denominator. No LDS in main loop.
//  kE : per-row log_softmax + w_lin partial sums
//  kF : out[8] = sum partials + b_lin -> d_out[0..8)

typedef __attribute__((ext_vector_type(8))) short bf16x8;   // MFMA A/B frag (4 VGPRs)
typedef __attribute__((ext_vector_type(4))) float f32x4;

#define NN 4096
#define NC 8

__device__ __forceinline__ short f2bf(float f) {
  __hip_bfloat16 h = __float2bfloat16(f);
  return *reinterpret_cast<short*>(&h);
}

__device__ __forceinline__ bool is_adj(const void* p) {
  const unsigned* u = (const unsigned*)p;
  unsigned m = u[0] | u[1] | u[2] | u[3] | u[100] | u[1000];
  return m <= 1u;   // adj dwords are 0/1; fp32 N(0,1) bits never <= 1
}

// ---------- kA0: W[h][f][o] fp32 -> Wt[h*8+o][f] bf16 ; WhT rows 8..15 init ----------
__global__ __launch_bounds__(256) void kA0(const float* __restrict__ W, short* __restrict__ Wt,
                                           short* __restrict__ WhT) {
  int idx = blockIdx.x * 256 + threadIdx.x;      // 131072
  int h = idx >> 15, r = idx & 32767, f = r >> 3, o = r & 7;
  Wt[(size_t)(h * 8 + o) * NN + f] = f2bf(W[idx]);
  // WhT init: 4 heads x 8 rows (n=8..15) x 4096 = 131072 elements exactly.
  int n2 = 8 + (r >> 12);       // 8..15
  int j2 = r & 4095;
  WhT[((size_t)(h * 16 + n2)) * NN + j2] = (n2 == 8) ? (short)0x3F80 : (short)0;  // bf16 1.0 / 0
}

// ---------- kA: Wh = x @ W via MFMA 16x16x32 bf16, + scores, WhT bf16 out ----------
// 256 blocks x 256 thr (4 waves). Block: 16 rows x 32 cols; wave w: k in [w*1024, (w+1)*1024).
// A-frag: A[m=lane&15][k=q*8+j]; B-frag: B[k=q*8+j][n=lane&15] (from Wt rows).
// D: n=lane&15, m=q*4+reg  [m89/m91-verified layout].
__global__ __launch_bounds__(256) void kA(const void* __restrict__ c0, const void* __restrict__ c1,
                                          const short* __restrict__ Wt,
                                          short* __restrict__ WhT, float* __restrict__ ssrc,
                                          float* __restrict__ sdst, const float* __restrict__ a) {
  const float* x = (const float*)(is_adj(c0) ? c1 : c0);
  int m0 = blockIdx.x * 16;
  int t = threadIdx.x;
  int w = t >> 6, lane = t & 63;
  int mr = lane & 15, q = lane >> 4;
  const f32x4*  ap  = (const f32x4*)(x + (size_t)(m0 + mr) * NN + w * 1024 + q * 8);
  const bf16x8* b0p = (const bf16x8*)(Wt + (size_t)mr        * NN + w * 1024 + q * 8);
  const bf16x8* b1p = (const bf16x8*)(Wt + (size_t)(16 + mr) * NN + w * 1024 + q * 8);
  f32x4 acc0 = {0.f, 0.f, 0.f, 0.f}, acc1 = {0.f, 0.f, 0.f, 0.f};
#pragma unroll 4
  for (int kk = 0; kk < 32; ++kk) {      // 32 k-steps of 32
    f32x4 xa = ap[kk * 8];
    f32x4 xb = ap[kk * 8 + 1];
    bf16x8 af;
#pragma unroll
    for (int e = 0; e < 4; ++e) { af[e] = f2bf(xa[e]); af[4 + e] = f2bf(xb[e]); }
    bf16x8 b0 = b0p[kk * 4];
    bf16x8 b1 = b1p[kk * 4];
    acc0 = __builtin_amdgcn_mfma_f32_16x16x32_bf16(af, b0, acc0, 0, 0, 0);
    acc1 = __builtin_amdgcn_mfma_f32_16x16x32_bf16(af, b1, acc1, 0, 0, 0);
  }
  __shared__ float red[4][16][32];
  __shared__ float whole[16][32];
#pragma unroll
  for (int r = 0; r < 4; ++r) {
    red[w][q * 4 + r][mr]      = acc0[r];
    red[w][q * 4 + r][16 + mr] = acc1[r];
  }
  __syncthreads();
  for (int idx = t; idx < 512; idx += 256) {
    int m = idx >> 5, c = idx & 31;
    float s = red[0][m][c] + red[1][m][c] + red[2][m][c] + red[3][m][c];
    whole[m][c] = s;
    int h = c >> 3, o = c & 7;
    WhT[((size_t)(h * 16 + o)) * NN + (m0 + m)] = f2bf(s);
  }
  __syncthreads();
  if (t < 64) {
    int h = t >> 4, m = t & 15;
    float s1 = 0.f, s2 = 0.f;
#pragma unroll
    for (int o = 0; o < 8; ++o) {
      float v = whole[m][h * 8 + o];
      s1 += v * a[h * 16 + o];
      s2 += v * a[h * 16 + 8 + o];
    }
    ssrc[h * NN + m0 + m] = s1;
    sdst[h * NN + m0 + m] = s2;
  }
}

// ---------- kC: per-head global max of s_dst ----------
__global__ __launch_bounds__(256) void kC(const float* __restrict__ sdst, float* __restrict__ mhat) {
  int h = blockIdx.x, t = threadIdx.x;
  float m = -1e30f;
  for (int n = t; n < NN; n += 256) m = fmaxf(m, sdst[h * NN + n]);
  for (int mm = 1; mm <= 32; mm <<= 1) m = fmaxf(m, __shfl_xor(m, mm));
  __shared__ float sm[4];
  if ((t & 63) == 0) sm[t >> 6] = m;
  __syncthreads();
  if (t == 0) mhat[h] = fmaxf(fmaxf(sm[0], sm[1]), fmaxf(sm[2], sm[3]));
}

// ---------- kD: MFMA attention + aggregation + head-mean -> fp32 node_emb ----------
// 256 blocks (i-tile of 16 rows) x 1024 thr = 16 waves: wave w -> head (w&3), j-quarter (w>>2).
// Per 32-j chunk: lane (n=lane&15, q=lane>>4) computes A[row n][k=q*8+jj] = exp-weight (bf16),
// loads B-frag from WhT[h][col n][j0+q*8..+7]; acc (16x16) col 8 = denominator (B ones-col).
// No LDS, no syncthreads in main loop; cross-wave combine at end.
__global__ __launch_bounds__(1024) void kD(const void* __restrict__ c0, const void* __restrict__ c1,
                                           const short* __restrict__ WhT,
                                           const float* __restrict__ ssrcg, const float* __restrict__ sdstg,
                                           const float* __restrict__ mhat,
                                           float* __restrict__ neF) {
  const int* adj = (const int*)(is_adj(c0) ? c0 : c1);
  __shared__ float red[16][16][10];
  int t = threadIdx.x;
  int w = t >> 6, lane = t & 63;
  int h = w & 3, qt = w >> 2;
  int n = lane & 15, q = lane >> 4;
  int i0 = blockIdx.x * 16;
  const float L2E = 1.4426950408889634f;     // log2(e): exp(x) = exp2(x*L2E)
  float mh  = mhat[h] * L2E;
  float ssr = ssrcg[h * NN + i0 + n] * L2E;
  float tb = ssr + mh;
  float eb = fmaxf(tb, 0.2f * tb);           // upper bound of scaled lrelu scores for row
  const float*  sdp  = sdstg + h * NN + qt * 1024 + q * 8;
  const int*    adjp = adj + (size_t)(i0 + n) * NN + qt * 1024 + q * 8;
  const bf16x8* bp   = (const bf16x8*)(WhT + ((size_t)(h * 16 + n)) * NN + qt * 1024 + q * 8);
  f32x4 acc = {0.f, 0.f, 0.f, 0.f};
#pragma unroll 2
  for (int c = 0; c < 32; ++c) {             // 32 chunks x 32 j = 1024 j per wave
    f32x4 sd0 = *(const f32x4*)(sdp + c * 32);
    f32x4 sd1 = *(const f32x4*)(sdp + c * 32 + 4);
    int4  av0 = *(const int4*)(adjp + c * 32);
    int4  av1 = *(const int4*)(adjp + c * 32 + 4);
    bf16x8 bf = bp[c * 4];
    int avs[8] = {av0.x, av0.y, av0.z, av0.w, av1.x, av1.y, av1.z, av1.w};
    float sdv[8] = {sd0[0], sd0[1], sd0[2], sd0[3], sd1[0], sd1[1], sd1[2], sd1[3]};
    bf16x8 af;
#pragma unroll
    for (int e = 0; e < 8; ++e) {
      float tt = fmaf(sdv[e], L2E, ssr);     // scaled score
      float ee = fmaxf(tt, 0.2f * tt);       // scaled lrelu
      float ww = __builtin_amdgcn_exp2f(ee - eb);
      ww = (avs[e] > 0) ? ww : 0.f;
      af[e] = f2bf(ww);
    }
    acc = __builtin_amdgcn_mfma_f32_16x16x32_bf16(af, bf, acc, 0, 0, 0);
  }
  // D layout: col = lane&15 (=n), rows q*4+r. Cols 0..7 = agg, col 8 = denom.
  if (n < 9) {
#pragma unroll
    for (int r = 0; r < 4; ++r) red[w][q * 4 + r][n] = acc[r];
  }
  __syncthreads();
  if (t < 128) {
    int i = t >> 3, o = t & 7;
    float tot = 0.f;
#pragma unroll
    for (int hh = 0; hh < 4; ++hh) {
      float s = 0.f, l = 0.f;
#pragma unroll
      for (int qq = 0; qq < 4; ++qq) {
        s += red[qq * 4 + hh][i][o];
        l += red[qq * 4 + hh][i][8];
      }
      tot += s / l;
    }
    neF[(size_t)(i0 + i) * NC + o] = 0.25f * tot;
  }
}

// ---------- kE: log_softmax rows + w_lin partial sums ----------
__global__ __launch_bounds__(128) void kE(const float* __restrict__ neF, const float* __restrict__ wlin,
                                          float* __restrict__ partials) {
  int t = threadIdx.x;
  int n = blockIdx.x * 128 + t;
  f32x4 v0 = *(const f32x4*)(neF + (size_t)n * NC);
  f32x4 v1 = *(const f32x4*)(neF + (size_t)n * NC + 4);
  float m = v0[0];
#pragma unroll
  for (int e = 1; e < 4; ++e) m = fmaxf(m, v0[e]);
#pragma unroll
  for (int e = 0; e < 4; ++e) m = fmaxf(m, v1[e]);
  float s = 0.f;
#pragma unroll
  for (int e = 0; e < 4; ++e) s += __expf(v0[e] - m);
#pragma unroll
  for (int e = 0; e < 4; ++e) s += __expf(v1[e] - m);
  float ln = m + __logf(s);
  float wl = wlin[n];
  float p[8];
#pragma unroll
  for (int e = 0; e < 4; ++e) p[e] = (v0[e] - ln) * wl;
#pragma unroll
  for (int e = 0; e < 4; ++e) p[4 + e] = (v1[e] - ln) * wl;
#pragma unroll
  for (int mm = 1; mm <= 32; mm <<= 1)
#pragma unroll
    for (int o = 0; o < 8; ++o) p[o] += __shfl_xor(p[o], mm);
  __shared__ float wsum[2][8];
  if ((t & 63) == 0)
#pragma unroll
    for (int o = 0; o < 8; ++o) wsum[t >> 6][o] = p[o];
  __syncthreads();
  if (t < 8) partials[blockIdx.x * 8 + t] = wsum[0][t] + wsum[1][t];
}

// ---------- kF: final out[8] ----------
__global__ __launch_bounds__(64) void kF(const float* __restrict__ partials, const float* __restrict__ blin,
                                         float* __restrict__ out) {
  int t = threadIdx.x;
  if (t < 8) {
    float s = blin[0];
    for (int b = 0; b < 32; ++b) s += partials[b * 8 + t];
    out[t] = s;
  }
}

extern "C" void kernel_launch(void* const* d_in, const int* in_sizes, int n_in,
                              void* d_out, int out_size, void* d_ws, size_t ws_size,
                              hipStream_t stream) {
  const void* big0 = nullptr; const void* big1 = nullptr;
  const float* W = nullptr; const float* a = nullptr;
  const float* wlin = nullptr; const float* blin = nullptr;
  for (int idx = 0; idx < n_in; ++idx) {
    int sz = in_sizes[idx];
    if (sz == NN * NN)          { if (!big0) big0 = d_in[idx]; else big1 = d_in[idx]; }
    else if (sz == 4 * NN * NC) W    = (const float*)d_in[idx];
    else if (sz == 64)          a    = (const float*)d_in[idx];
    else if (sz == NN)          wlin = (const float*)d_in[idx];
    else if (sz == 1)           blin = (const float*)d_in[idx];
  }
  float* outF = (float*)d_out;       // fp32: [8] out | [4096][8] node_embeddings
  float* neF  = outF + 8;

  char* ws = (char*)d_ws;                 // 918,784 B total
  short* Wt      = (short*)(ws + 0);      // 262144 B
  short* WhT     = (short*)(ws + 262144); // 524288 B : [4h][16 cols][4096] bf16 (col8=1, 9..15=0)
  float* ssrc    = (float*)(ws + 786432); // 65536 B
  float* sdst    = (float*)(ws + 851968); // 65536 B
  float* mhat    = (float*)(ws + 917504); // 256 B
  float* partials= (float*)(ws + 917760); // 1024 B

  kA0<<<512, 256, 0, stream>>>(W, Wt, WhT);
  kA <<<256, 256, 0, stream>>>(big0, big1, Wt, WhT, ssrc, sdst, a);
  kC <<<4,   256, 0, stream>>>(sdst, mhat);
  kD <<<256, 1024, 0, stream>>>(big0, big1, WhT, ssrc, sdst, mhat, neF);
  kE <<<32,  128, 0, stream>>>(neF, wlin, partials);
  kF <<<1,   64,  0, stream>>>(partials, blin, outF);
}

// Round 3
// 181.621 us; speedup vs baseline: 1.1170x; 1.1033x over previous
//
#include <hip/hip_runtime.h>
#include <hip/hip_bf16.h>

// GAT on MI355X. Inputs fp32 (+ int32 adj); output fp32 [8 | 4096*8].
//  kA0: W -> Wt bf16 (B-layout); WhT rows 8..15 init (col8=ones); mhat/out init
//  kA : Wh = x @ W via MFMA (16 waves, K split 16x256); epilogue: WhT bf16,
//       s_src/s_dst scores, per-head sdst max via encoded-float atomicMax
//  kD : MFMA attention, 4 heads per wave (adj reuse), explicit adj prefetch;
//       epilogue: head-mean -> neF, fused log_softmax + w_lin reduce -> atomicAdd out
typedef __attribute__((ext_vector_type(8))) short bf16x8;
typedef __attribute__((ext_vector_type(4))) float f32x4;

#define NN 4096
#define NC 8

__device__ __forceinline__ short f2bf(float f) {
  __hip_bfloat16 h = __float2bfloat16(f);
  return *reinterpret_cast<short*>(&h);
}
__device__ __forceinline__ unsigned fenc(float v) {
  int b = __float_as_int(v);
  return (b >= 0) ? ((unsigned)b | 0x80000000u) : (unsigned)(~b);
}
__device__ __forceinline__ float fdec(unsigned k) {
  int b = (k & 0x80000000u) ? (int)(k & 0x7FFFFFFFu) : ~(int)k;
  return __int_as_float(b);
}
__device__ __forceinline__ bool is_adj(const void* p) {
  const unsigned* u = (const unsigned*)p;
  unsigned m = u[0] | u[1] | u[2] | u[3] | u[100] | u[1000];
  return m <= 1u;
}

// ---------- kA0 ----------
__global__ __launch_bounds__(256) void kA0(const float* __restrict__ W, short* __restrict__ Wt,
                                           short* __restrict__ WhT, const float* __restrict__ blin,
                                           float* __restrict__ outF, unsigned* __restrict__ mhatU) {
  int t = threadIdx.x;
  int idx = blockIdx.x * 256 + t;            // 131072
  int h = idx >> 15, r = idx & 32767, f = r >> 3, o = r & 7;
  Wt[(size_t)(h * 8 + o) * NN + f] = f2bf(W[idx]);
  int n2 = 8 + (r >> 12);
  int j2 = r & 4095;
  WhT[((size_t)(h * 16 + n2)) * NN + j2] = (n2 == 8) ? (short)0x3F80 : (short)0;
  if (blockIdx.x == 0) {
    if (t < 4) mhatU[t] = 0u;
    if (t >= 8 && t < 16) outF[t - 8] = blin[0];
  }
}

// ---------- kA: 256 blocks x 1024 thr (16 waves). wave w: k in [w*256,(w+1)*256) ----------
__global__ __launch_bounds__(1024) void kA(const void* __restrict__ c0, const void* __restrict__ c1,
                                           const short* __restrict__ Wt,
                                           short* __restrict__ WhT, float* __restrict__ ssrc,
                                           float* __restrict__ sdst, const float* __restrict__ a,
                                           unsigned* __restrict__ mhatU) {
  const float* x = (const float*)(is_adj(c0) ? c1 : c0);
  int m0 = blockIdx.x * 16;
  int t = threadIdx.x;
  int w = t >> 6, lane = t & 63;
  int mr = lane & 15, q = lane >> 4;
  const f32x4*  ap  = (const f32x4*)(x + (size_t)(m0 + mr) * NN + w * 256 + q * 8);
  const bf16x8* b0p = (const bf16x8*)(Wt + (size_t)mr        * NN + w * 256 + q * 8);
  const bf16x8* b1p = (const bf16x8*)(Wt + (size_t)(16 + mr) * NN + w * 256 + q * 8);
  f32x4 acc0 = {0.f, 0.f, 0.f, 0.f}, acc1 = {0.f, 0.f, 0.f, 0.f};
#pragma unroll 4
  for (int kk = 0; kk < 8; ++kk) {           // 8 k-steps of 32
    f32x4 xa = ap[kk * 8];
    f32x4 xb = ap[kk * 8 + 1];
    bf16x8 af;
#pragma unroll
    for (int e = 0; e < 4; ++e) { af[e] = f2bf(xa[e]); af[4 + e] = f2bf(xb[e]); }
    bf16x8 b0 = b0p[kk * 4];
    bf16x8 b1 = b1p[kk * 4];
    acc0 = __builtin_amdgcn_mfma_f32_16x16x32_bf16(af, b0, acc0, 0, 0, 0);
    acc1 = __builtin_amdgcn_mfma_f32_16x16x32_bf16(af, b1, acc1, 0, 0, 0);
  }
  __shared__ float red[16][16][32];
  __shared__ float whole[16][32];
#pragma unroll
  for (int r = 0; r < 4; ++r) {
    red[w][q * 4 + r][mr]      = acc0[r];
    red[w][q * 4 + r][16 + mr] = acc1[r];
  }
  __syncthreads();
  if (t < 512) {
    int m = t >> 5, c = t & 31;
    float s = 0.f;
#pragma unroll
    for (int ww = 0; ww < 16; ++ww) s += red[ww][m][c];
    whole[m][c] = s;
    int h = c >> 3, o = c & 7;
    WhT[((size_t)(h * 16 + o)) * NN + (m0 + m)] = f2bf(s);
  }
  __syncthreads();
  if (t < 64) {
    int h = t >> 4, m = t & 15;
    float s1 = 0.f, s2 = 0.f;
#pragma unroll
    for (int o = 0; o < 8; ++o) {
      float v = whole[m][h * 8 + o];
      s1 += v * a[h * 16 + o];
      s2 += v * a[h * 16 + 8 + o];
    }
    ssrc[h * NN + m0 + m] = s1;
    sdst[h * NN + m0 + m] = s2;
    float mx = s2;
#pragma unroll
    for (int mm = 1; mm <= 8; mm <<= 1) mx = fmaxf(mx, __shfl_xor(mx, mm));
    if ((t & 15) == 0) atomicMax(&mhatU[h], fenc(mx));
  }
}

// ---------- kD: 256 blocks x 1024 thr (16 waves). wave w -> j in [w*256,(w+1)*256), all 4 heads ----------
#define HEAD_STEP(H, ACC)                                                 \
  {                                                                       \
    f32x4 s0 = sp##H[c * 8], s1 = sp##H[c * 8 + 1];                       \
    bf16x8 bv = bp##H[c * 4];                                             \
    bf16x8 af;                                                            \
    _Pragma("unroll")                                                     \
    for (int e = 0; e < 4; ++e) {                                         \
      float tt = fmaf(s0[e], L2E, ssr##H);                                \
      float ee = fmaxf(tt, 0.2f * tt);                                    \
      float wv = __builtin_amdgcn_exp2f(ee - eb##H);                      \
      af[e] = f2bf(mk[e] ? wv : 0.f);                                     \
    }                                                                     \
    _Pragma("unroll")                                                     \
    for (int e = 0; e < 4; ++e) {                                         \
      float tt = fmaf(s1[e], L2E, ssr##H);                                \
      float ee = fmaxf(tt, 0.2f * tt);                                    \
      float wv = __builtin_amdgcn_exp2f(ee - eb##H);                      \
      af[4 + e] = f2bf(mk[4 + e] ? wv : 0.f);                             \
    }                                                                     \
    ACC = __builtin_amdgcn_mfma_f32_16x16x32_bf16(af, bv, ACC, 0, 0, 0);  \
  }

__global__ __launch_bounds__(1024) void kD(const void* __restrict__ c0, const void* __restrict__ c1,
                                           const short* __restrict__ WhT,
                                           const float* __restrict__ ssrcg, const float* __restrict__ sdstg,
                                           const unsigned* __restrict__ mhatU,
                                           const float* __restrict__ wlin,
                                           float* __restrict__ outF, float* __restrict__ neF) {
  const int* adj = (const int*)(is_adj(c0) ? c0 : c1);
  __shared__ float red[16][4][16][10];     // 40 KB
  __shared__ float ps[2][8];
  int t = threadIdx.x;
  int w = t >> 6, lane = t & 63;
  int n = lane & 15, q = lane >> 4;
  int i0 = blockIdx.x * 16;
  int j0 = w * 256;
  const float L2E = 1.4426950408889634f;
  float mh0 = fdec(mhatU[0]) * L2E, mh1 = fdec(mhatU[1]) * L2E;
  float mh2 = fdec(mhatU[2]) * L2E, mh3 = fdec(mhatU[3]) * L2E;
  float ssr0 = ssrcg[0 * NN + i0 + n] * L2E;
  float ssr1 = ssrcg[1 * NN + i0 + n] * L2E;
  float ssr2 = ssrcg[2 * NN + i0 + n] * L2E;
  float ssr3 = ssrcg[3 * NN + i0 + n] * L2E;
  float tb0 = ssr0 + mh0, tb1 = ssr1 + mh1, tb2 = ssr2 + mh2, tb3 = ssr3 + mh3;
  float eb0 = fmaxf(tb0, 0.2f * tb0), eb1 = fmaxf(tb1, 0.2f * tb1);
  float eb2 = fmaxf(tb2, 0.2f * tb2), eb3 = fmaxf(tb3, 0.2f * tb3);
  const int*    adjp = adj + (size_t)(i0 + n) * NN + j0 + q * 8;
  const f32x4*  sp0 = (const f32x4*)(sdstg + 0 * NN + j0 + q * 8);
  const f32x4*  sp1 = (const f32x4*)(sdstg + 1 * NN + j0 + q * 8);
  const f32x4*  sp2 = (const f32x4*)(sdstg + 2 * NN + j0 + q * 8);
  const f32x4*  sp3 = (const f32x4*)(sdstg + 3 * NN + j0 + q * 8);
  const bf16x8* bp0 = (const bf16x8*)(WhT + (size_t)(0 * 16 + n) * NN + j0 + q * 8);
  const bf16x8* bp1 = (const bf16x8*)(WhT + (size_t)(1 * 16 + n) * NN + j0 + q * 8);
  const bf16x8* bp2 = (const bf16x8*)(WhT + (size_t)(2 * 16 + n) * NN + j0 + q * 8);
  const bf16x8* bp3 = (const bf16x8*)(WhT + (size_t)(3 * 16 + n) * NN + j0 + q * 8);
  f32x4 acc0 = {0.f,0.f,0.f,0.f}, acc1 = {0.f,0.f,0.f,0.f};
  f32x4 acc2 = {0.f,0.f,0.f,0.f}, acc3 = {0.f,0.f,0.f,0.f};
  int4 na0 = *(const int4*)(adjp);
  int4 na1 = *(const int4*)(adjp + 4);
#pragma unroll 2
  for (int c = 0; c < 8; ++c) {            // 8 chunks x 32 j
    int4 a0 = na0, a1 = na1;
    if (c < 7) {
      na0 = *(const int4*)(adjp + (c + 1) * 32);
      na1 = *(const int4*)(adjp + (c + 1) * 32 + 4);
    }
    int avs[8] = {a0.x, a0.y, a0.z, a0.w, a1.x, a1.y, a1.z, a1.w};
    bool mk[8];
#pragma unroll
    for (int e = 0; e < 8; ++e) mk[e] = avs[e] > 0;
    HEAD_STEP(0, acc0)
    HEAD_STEP(1, acc1)
    HEAD_STEP(2, acc2)
    HEAD_STEP(3, acc3)
  }
  if (n < 9) {
#pragma unroll
    for (int r = 0; r < 4; ++r) {
      red[w][0][q * 4 + r][n] = acc0[r];
      red[w][1][q * 4 + r][n] = acc1[r];
      red[w][2][q * 4 + r][n] = acc2[r];
      red[w][3][q * 4 + r][n] = acc3[r];
    }
  }
  __syncthreads();
  if (t < 128) {
    int i = t >> 3, o = t & 7;
    float tot = 0.f;
#pragma unroll
    for (int h = 0; h < 4; ++h) {
      float s = 0.f, l = 0.f;
#pragma unroll
      for (int ww = 0; ww < 16; ++ww) {
        s += red[ww][h][i][o];
        l += red[ww][h][i][8];
      }
      tot += s / l;
    }
    float ne = 0.25f * tot;
    neF[(size_t)(i0 + i) * NC + o] = ne;
    // fused log_softmax over o (8 lanes per row) + w_lin partial
    float m = ne;
#pragma unroll
    for (int mm = 1; mm <= 4; mm <<= 1) m = fmaxf(m, __shfl_xor(m, mm));
    float ex = __expf(ne - m);
    float s8 = ex;
#pragma unroll
    for (int mm = 1; mm <= 4; mm <<= 1) s8 += __shfl_xor(s8, mm);
    float ln = m + __logf(s8);
    float p = (ne - ln) * wlin[i0 + i];
#pragma unroll
    for (int mm = 8; mm <= 32; mm <<= 1) p += __shfl_xor(p, mm);
    if ((t & 63) < 8) ps[t >> 6][t & 7] = p;
  }
  __syncthreads();
  if (t < 8) atomicAdd(&outF[t], ps[0][t] + ps[1][t]);
}

extern "C" void kernel_launch(void* const* d_in, const int* in_sizes, int n_in,
                              void* d_out, int out_size, void* d_ws, size_t ws_size,
                              hipStream_t stream) {
  const void* big0 = nullptr; const void* big1 = nullptr;
  const float* W = nullptr; const float* a = nullptr;
  const float* wlin = nullptr; const float* blin = nullptr;
  for (int idx = 0; idx < n_in; ++idx) {
    int sz = in_sizes[idx];
    if (sz == NN * NN)          { if (!big0) big0 = d_in[idx]; else big1 = d_in[idx]; }
    else if (sz == 4 * NN * NC) W    = (const float*)d_in[idx];
    else if (sz == 64)          a    = (const float*)d_in[idx];
    else if (sz == NN)          wlin = (const float*)d_in[idx];
    else if (sz == 1)           blin = (const float*)d_in[idx];
  }
  float* outF = (float*)d_out;       // fp32: [8] out | [4096][8] node_embeddings
  float* neF  = outF + 8;

  char* ws = (char*)d_ws;
  short*    Wt    = (short*)(ws + 0);       // 262144 B
  short*    WhT   = (short*)(ws + 262144);  // 524288 B : [4h][16][4096] bf16 (col8=1)
  float*    ssrc  = (float*)(ws + 786432);  // 65536 B
  float*    sdst  = (float*)(ws + 851968);  // 65536 B
  unsigned* mhatU = (unsigned*)(ws + 917504); // 16 B

  kA0<<<512, 256, 0, stream>>>(W, Wt, WhT, blin, outF, mhatU);
  kA <<<256, 1024, 0, stream>>>(big0, big1, Wt, WhT, ssrc, sdst, a, mhatU);
  kD <<<256, 1024, 0, stream>>>(big0, big1, WhT, ssrc, sdst, mhatU, wlin, outF, neF);
}